// Round 21
// baseline (191.314 us; speedup 1.0000x reference)
//
#include <hip/hip_runtime.h>
#include <hip/hip_bf16.h>

#define NB 32768      // batch rows per node
#define CD 128        // input channels (K of every GEMM term)
#define OUTW 1536     // 6*256 output cols
#define GPB 8         // row-groups per persistent block
#define NBLK (NB / 16 / GPB)   // 256 blocks = 1 per CU

// d_ws weight matrices, each [256 out][128 k] bf16 (32768 shorts):
#define PW_P  0        // Wl            (U = T·Wl)
#define PW_M0 32768    // Wr - Wl/5     (nodes 0,1)
#define PW_M2 65536    // Wr - Wl/4     (nodes 2..5 own term)
#define PW_N  98304    // -Wl/4         (partner term)

typedef __attribute__((ext_vector_type(8))) short short8;
typedef __attribute__((ext_vector_type(4))) float f32x4;

static __device__ __forceinline__ short f2bf(float f) {
    union { __bf16 b; short s; } u;
    u.b = (__bf16)f;
    return u.s;
}

static __device__ __forceinline__ short8 pack8(f32x4 a, f32x4 b) {
    short8 p;
    #pragma unroll
    for (int j = 0; j < 4; ++j) { p[j] = f2bf(a[j]); p[4 + j] = f2bf(b[j]); }
    return p;
}

// ---- prologue: 4 combined weight matrices (R18-validated, absmax 0.03125)
__global__ void prep_w(const float* __restrict__ Wl, const float* __restrict__ Wr,
                       short* __restrict__ Wb) {
    const int i = (blockIdx.x * 256 + threadIdx.x) * 8;   // o*128 + k
    const int o = i >> 7;
    const int k = i & 127;
    f32x4 l0 = *(const f32x4*)(Wl + o * CD + k);
    f32x4 l1 = *(const f32x4*)(Wl + o * CD + k + 4);
    f32x4 r0 = *(const f32x4*)(Wr + o * CD + k);
    f32x4 r1 = *(const f32x4*)(Wr + o * CD + k + 4);
    *(short8*)(Wb + PW_P  + i) = pack8(l0, l1);
    *(short8*)(Wb + PW_M0 + i) = pack8(r0 - 0.2f  * l0, r1 - 0.2f  * l1);
    *(short8*)(Wb + PW_M2 + i) = pack8(r0 - 0.25f * l0, r1 - 0.25f * l1);
    *(short8*)(Wb + PW_N  + i) = pack8(-0.25f * l0, -0.25f * l1);
}

// LDS short-index XOR swizzle (byte ^= (r&7)<<4); bijective for 16B granules,
// reads 2-way max. Verified R5-R18. Panels: 0..5 = x0..x5, 6 = T.
#define LIDX(p, r, k) ((((p) << 11) + ((r) << 7) + (k)) ^ (((r) & 7) << 3))

// R21 = R20 with the cross-wave raw race FIXED: stage chunk mapping now
// matches convert's row mapping per wave (wave q stages floats
// [512q,512q+512) = rows [4q,4q+4); its convert lanes read exactly r in
// [4q,4q+4)) -> per-wave vmcnt correctly orders DMA before its own reads.
// Structure: waves 0-3 COMPUTE (64-col strip, R18 algebra, setprio around
// MFMA), waves 4-7 STAGE+CONVERT (DMA depth 2, counted vmcnt(12)); raw
// s_barrier + lgkmcnt(0) only -- stores never force-drained.
__global__ __launch_bounds__(512, 1)
void sage_v19(const float* __restrict__ x, const short* __restrict__ Wb,
              const float* __restrict__ bias, float* __restrict__ out) {
    __shared__ __align__(16) float raw[2][6 * 16 * 128];   // 2 x 48 KB
    __shared__ __align__(16) short A[2][7 * 16 * 128];     // 2 x 28 KB

    const int t = threadIdx.x;
    const int lane = t & 63;
    const int wv = t >> 6;
    const int lo = lane & 15;
    const int hi = lane >> 4;
    const size_t rg0 = (size_t)blockIdx.x * GPB;

    // ================= convert-wave machinery (waves 4..7) =================
    auto stage = [&](int buf, size_t rg) {     // 12 global_load_lds per wave
        const int q = wv - 4;
        const size_t gbase = rg * 16 * CD;
        #pragma unroll
        for (int s = 0; s < 6; ++s)
            #pragma unroll
            for (int j = 0; j < 2; ++j) {
                // RACE FIX: wave q owns chunks {2q, 2q+1} = rows [4q, 4q+4)
                const int off = (q * 2 + j) * 256;
                __builtin_amdgcn_global_load_lds(
                    (const __attribute__((address_space(1))) void*)
                        (x + (size_t)s * (NB * CD) + gbase + off + (lane << 2)),
                    (__attribute__((address_space(3))) void*)&raw[buf][s * 2048 + off],
                    16, 0, 0);
            }
    };
    auto convert = [&](int buf) {              // wave 4+q covers r in [4q,4q+4)
        const int u = t & 255;
        const int r = u >> 4;
        const int c = u & 15;                  // 8-float chunk
        const float* rb = &raw[buf][0];
        const int base = r * 128 + c * 8;
        f32x4 a0 = *(const f32x4*)&rb[0 * 2048 + base], b0 = *(const f32x4*)&rb[0 * 2048 + base + 4];
        f32x4 a1 = *(const f32x4*)&rb[1 * 2048 + base], b1 = *(const f32x4*)&rb[1 * 2048 + base + 4];
        f32x4 a2 = *(const f32x4*)&rb[2 * 2048 + base], b2 = *(const f32x4*)&rb[2 * 2048 + base + 4];
        f32x4 a3 = *(const f32x4*)&rb[3 * 2048 + base], b3 = *(const f32x4*)&rb[3 * 2048 + base + 4];
        f32x4 a4 = *(const f32x4*)&rb[4 * 2048 + base], b4 = *(const f32x4*)&rb[4 * 2048 + base + 4];
        f32x4 a5 = *(const f32x4*)&rb[5 * 2048 + base], b5 = *(const f32x4*)&rb[5 * 2048 + base + 4];
        f32x4 Ta = ((a0 + a1) + (a2 + a3)) + (a4 + a5);
        f32x4 Tb = ((b0 + b1) + (b2 + b3)) + (b4 + b5);
        short* Ad = &A[buf][0];
        const int k = c * 8;
        *(short8*)&Ad[LIDX(0, r, k)] = pack8(a0, b0);
        *(short8*)&Ad[LIDX(1, r, k)] = pack8(a1, b1);
        *(short8*)&Ad[LIDX(2, r, k)] = pack8(a2, b2);
        *(short8*)&Ad[LIDX(3, r, k)] = pack8(a3, b3);
        *(short8*)&Ad[LIDX(4, r, k)] = pack8(a4, b4);
        *(short8*)&Ad[LIDX(5, r, k)] = pack8(a5, b5);
        *(short8*)&Ad[LIDX(6, r, k)] = pack8(Ta, Tb);
    };

    // ================= compute-wave machinery (waves 0..3) =================
    const int obase = wv * 64;                 // valid for wv<4
    f32x4 bias4[4];
    if (wv < 4) {
        #pragma unroll
        for (int i = 0; i < 4; ++i)
            bias4[i] = *(const f32x4*)&bias[obase + i * 16 + hi * 4];
    }
    auto storePair = [&](int n0, int n1, f32x4 acc[2][4], size_t orow) {
        #pragma unroll
        for (int w = 0; w < 2; ++w) {
            const int node = w ? n1 : n0;
            #pragma unroll
            for (int i = 0; i < 4; ++i) {
                const int ocol = obase + i * 16 + hi * 4;
                f32x4 v = acc[w][i] + bias4[i];
                f32x4 g;
                #pragma unroll
                for (int j = 0; j < 4; ++j) {
                    const float s = v[j] * (0.7978845608f + 0.0356774081f * v[j] * v[j]);
                    const float rr = __builtin_amdgcn_exp2f(-2.885390082f * s);
                    g[j] = v[j] * __builtin_amdgcn_rcpf(1.0f + rr);
                }
                *(f32x4*)&out[orow * OUTW + node * 256 + ocol] = g;
            }
        }
    };
    auto pairMFMA = [&](const short* Ab, int p0, int p1, int mOwn, int mN,
                        f32x4 acc[2][4]) {
        #pragma unroll
        for (int n = 0; n < 2; ++n)
            #pragma unroll
            for (int i = 0; i < 4; ++i) acc[n][i] = (f32x4){0.f,0.f,0.f,0.f};
        __builtin_amdgcn_s_setprio(1);
        #pragma unroll
        for (int m = 0; m < 4; ++m) {
            const int kk = m * 32 + hi * 8;
            short8 fa = *(const short8*)&Ab[LIDX(p0, lo, kk)];
            short8 fb = *(const short8*)&Ab[LIDX(p1, lo, kk)];
            #pragma unroll
            for (int i = 0; i < 4; ++i) {
                const int widx = (obase + i * 16 + lo) * CD + kk;
                short8 wm = *(const short8*)&Wb[mOwn + widx];
                acc[0][i] = __builtin_amdgcn_mfma_f32_16x16x32_bf16(wm, fa, acc[0][i], 0, 0, 0);
                acc[1][i] = __builtin_amdgcn_mfma_f32_16x16x32_bf16(wm, fb, acc[1][i], 0, 0, 0);
                if (mN >= 0) {
                    short8 wn = *(const short8*)&Wb[mN + widx];
                    acc[0][i] = __builtin_amdgcn_mfma_f32_16x16x32_bf16(wn, fb, acc[0][i], 0, 0, 0);
                    acc[1][i] = __builtin_amdgcn_mfma_f32_16x16x32_bf16(wn, fa, acc[1][i], 0, 0, 0);
                }
            }
        }
        __builtin_amdgcn_s_setprio(0);
    };

    // ================= prologue =================
    if (wv >= 4) {
        stage(0, rg0);
        asm volatile("s_waitcnt vmcnt(0)" ::: "memory");
        convert(0);
        if (GPB > 1) stage(1, rg0 + 1);
    }
    asm volatile("s_waitcnt lgkmcnt(0)" ::: "memory");
    __builtin_amdgcn_s_barrier();

    f32x4 accH[2][4];              // compute waves: pair (3,4) held
    size_t prevRow = 0;

    #pragma unroll 1
    for (int it = 0; it < GPB; ++it) {
        if (wv < 4) {
            const short* Ab = &A[it & 1][0];
            const size_t orow = (rg0 + it) * 16 + lo;
            if (it) storePair(3, 4, accH, prevRow);      // full phase to drain

            // U-pass
            f32x4 accU[4];
            #pragma unroll
            for (int i = 0; i < 4; ++i) accU[i] = (f32x4){0.f,0.f,0.f,0.f};
            __builtin_amdgcn_s_setprio(1);
            #pragma unroll
            for (int m = 0; m < 4; ++m) {
                const int kk = m * 32 + hi * 8;
                short8 ft = *(const short8*)&Ab[LIDX(6, lo, kk)];
                #pragma unroll
                for (int i = 0; i < 4; ++i) {
                    short8 wp = *(const short8*)&Wb[PW_P + (obase + i * 16 + lo) * CD + kk];
                    accU[i] = __builtin_amdgcn_mfma_f32_16x16x32_bf16(wp, ft, accU[i], 0, 0, 0);
                }
            }
            __builtin_amdgcn_s_setprio(0);

            f32x4 acc[2][4];
            pairMFMA(Ab, 0, 1, PW_M0, -1, acc);          // nodes 0,1
            #pragma unroll
            for (int n = 0; n < 2; ++n)
                #pragma unroll
                for (int i = 0; i < 4; ++i) acc[n][i] += 0.2f * accU[i];
            storePair(0, 1, acc, orow);

            pairMFMA(Ab, 2, 5, PW_M2, PW_N, acc);        // nodes 2,5
            #pragma unroll
            for (int n = 0; n < 2; ++n)
                #pragma unroll
                for (int i = 0; i < 4; ++i) acc[n][i] += 0.25f * accU[i];
            storePair(2, 5, acc, orow);

            pairMFMA(Ab, 3, 4, PW_M2, PW_N, accH);       // nodes 3,4 -> held
            #pragma unroll
            for (int n = 0; n < 2; ++n)
                #pragma unroll
                for (int i = 0; i < 4; ++i) accH[n][i] += 0.25f * accU[i];
            prevRow = orow;
        } else {
            if (it + 1 < GPB) {
                if (it + 2 < GPB) {
                    stage(it & 1, rg0 + it + 2);                 // 12 newest
                    asm volatile("s_waitcnt vmcnt(12)" ::: "memory");  // DMA(it+1) done
                } else {
                    asm volatile("s_waitcnt vmcnt(0)" ::: "memory");
                }
                convert((it + 1) & 1);
            }
        }
        asm volatile("s_waitcnt lgkmcnt(0)" ::: "memory");
        __builtin_amdgcn_s_barrier();        // publish A[(it+1)&1]; no store drain
    }
    if (wv < 4) storePair(3, 4, accH, prevRow);
}

extern "C" void kernel_launch(void* const* d_in, const int* in_sizes, int n_in,
                              void* d_out, int out_size, void* d_ws, size_t ws_size,
                              hipStream_t stream) {
    const float* x  = (const float*)d_in[0];
    const float* Wl = (const float*)d_in[1];
    const float* Wr = (const float*)d_in[2];
    const float* b  = (const float*)d_in[3];
    float* out = (float*)d_out;
    short* Wb = (short*)d_ws;   // 4 x 64 KB bf16 weight combos = 256 KB

    prep_w<<<dim3(16), dim3(256), 0, stream>>>(Wl, Wr, Wb);
    sage_v19<<<dim3(NBLK), dim3(512), 0, stream>>>(x, Wb, b, out);
}